// Round 1
// baseline (2353.951 us; speedup 1.0000x reference)
//
#include <hip/hip_runtime.h>
#include <hip/hip_bf16.h>

#define NS_N 100000
#define NE_N 100000
#define EDG_N 1600000
#define DIM 256
#define NH 8
#define HDIM 32
#define FEAT_N 64
#define DFF_N 512

using bf16 = __hip_bfloat16;

__device__ __forceinline__ float toF(float x) { return x; }
__device__ __forceinline__ float toF(bf16 x) { return __bfloat162float(x); }

template <class T> __device__ __forceinline__ T fromF(float x);
template <> __device__ __forceinline__ float fromF<float>(float x) { return x; }
template <> __device__ __forceinline__ bf16 fromF<bf16>(float x) { return __float2bfloat16(x); }

// ---- repack [H][K][32] weight -> [K][H*32] row-major ----
__global__ void repack_w(const float* __restrict__ src, float* __restrict__ dst, int K) {
    int idx = blockIdx.x * 256 + threadIdx.x;
    if (idx >= K * 256) return;
    int i = idx >> 8;
    int c = idx & 255;
    int h = c >> 5;
    int o = c & 31;
    dst[idx] = src[(size_t)(h * K + i) * 32 + o];
}

// ---- CSR build ----
__global__ void count_edges(const int* __restrict__ edst, int* __restrict__ counts) {
    int t = blockIdx.x * 256 + threadIdx.x;
    if (t < EDG_N) atomicAdd(&counts[edst[t]], 1);
}

__global__ void scan_block(const int* __restrict__ counts, int* __restrict__ partial,
                           int* __restrict__ chunk) {
    __shared__ int sh[512];
    int i = blockIdx.x * 512 + threadIdx.x;
    int v = (i < NS_N) ? counts[i] : 0;
    sh[threadIdx.x] = v;
    __syncthreads();
    for (int off = 1; off < 512; off <<= 1) {
        int x = (threadIdx.x >= off) ? sh[threadIdx.x - off] : 0;
        __syncthreads();
        sh[threadIdx.x] += x;
        __syncthreads();
    }
    if (i < NS_N) partial[i] = sh[threadIdx.x] - v;  // exclusive
    if (threadIdx.x == 511) chunk[blockIdx.x] = sh[511];
}

__global__ void scan_chunks(int* __restrict__ chunk, int nc) {
    __shared__ int sh[256];
    int t = threadIdx.x;
    int v = (t < nc) ? chunk[t] : 0;
    sh[t] = v;
    __syncthreads();
    for (int off = 1; off < 256; off <<= 1) {
        int x = (t >= off) ? sh[t - off] : 0;
        __syncthreads();
        sh[t] += x;
        __syncthreads();
    }
    if (t < nc) chunk[t] = sh[t] - v;  // exclusive
}

__global__ void add_offsets(int* __restrict__ rowst, const int* __restrict__ chunk,
                            int* __restrict__ cursor) {
    int i = blockIdx.x * 256 + threadIdx.x;
    if (i < NS_N) {
        int r = rowst[i] + chunk[i >> 9];
        rowst[i] = r;
        cursor[i] = r;
    }
}

__global__ void scatter_edges(const int* __restrict__ esrc, const int* __restrict__ edst,
                              int* __restrict__ cursor, int* __restrict__ csr) {
    int t = blockIdx.x * 256 + threadIdx.x;
    if (t < EDG_N) {
        int d = edst[t];
        int pos = atomicAdd(&cursor[d], 1);
        csr[pos] = esrc[t];
    }
}

// ---- generic tiled GEMM: C[M,N] = act(A[M,K] @ B[K,N] + bias) + res ----
// A is split: k < KA0 from A0 (type TA), k >= KA0 from A1 (fp32).
template <class TA, class TC, bool BIAS, bool GELU, bool RES>
__global__ __launch_bounds__(256) void gemm_k(
    const TA* __restrict__ A0, const float* __restrict__ A1, int KA0,
    const float* __restrict__ B, const float* __restrict__ bias,
    const float* __restrict__ res, TC* __restrict__ C, int M, int N, int K) {
    __shared__ float As[8][128];
    __shared__ float Bs[8][128];
    int tid = threadIdx.x;
    int m0 = blockIdx.y * 128, n0 = blockIdx.x * 128;
    int tr = tid >> 4, tc = tid & 15;
    float acc[8][8];
#pragma unroll
    for (int i = 0; i < 8; i++)
#pragma unroll
        for (int j = 0; j < 8; j++) acc[i][j] = 0.f;

    int ar = tid >> 1, ak = (tid & 1) * 4;
    int bk = tid >> 5, bn = (tid & 31) * 4;
    int KA1 = K - KA0;

    for (int kk = 0; kk < K; kk += 8) {
        int row = m0 + ar;
#pragma unroll
        for (int j = 0; j < 4; j++) {
            int k = kk + ak + j;
            float v = 0.f;
            if (row < M) {
                if (k < KA0)
                    v = toF(A0[(size_t)row * KA0 + k]);
                else
                    v = A1[(size_t)row * KA1 + (k - KA0)];
            }
            As[ak + j][ar] = v;
        }
#pragma unroll
        for (int j = 0; j < 4; j++) {
            Bs[bk][bn + j] = B[(size_t)(kk + bk) * N + n0 + bn + j];
        }
        __syncthreads();
#pragma unroll
        for (int k = 0; k < 8; k++) {
            float a[8], b[8];
#pragma unroll
            for (int i = 0; i < 8; i++) a[i] = As[k][tr * 8 + i];
#pragma unroll
            for (int j = 0; j < 8; j++) b[j] = Bs[k][tc * 8 + j];
#pragma unroll
            for (int i = 0; i < 8; i++)
#pragma unroll
                for (int j = 0; j < 8; j++) acc[i][j] = fmaf(a[i], b[j], acc[i][j]);
        }
        __syncthreads();
    }

#pragma unroll
    for (int i = 0; i < 8; i++) {
        int row = m0 + tr * 8 + i;
        if (row >= M) continue;
#pragma unroll
        for (int j = 0; j < 8; j++) {
            int col = n0 + tc * 8 + j;
            float v = acc[i][j];
            if (BIAS) v += bias[col];
            if (GELU) {
                float x = v;
                v = 0.5f * x * (1.f + tanhf(0.7978845608028654f * (x + 0.044715f * x * x * x)));
            }
            if (RES) v += res[(size_t)row * N + col];
            C[(size_t)row * N + col] = fromF<TC>(v);
        }
    }
}

// ---- fused edge-softmax attention: one block (256 thr) per dst node ----
// thread t = output channel; head = t>>5 (32-thread subgroup, wave-aligned)
__global__ __launch_bounds__(256) void attn_k(
    const bf16* __restrict__ z, const bf16* __restrict__ df,
    const int* __restrict__ rowst, const int* __restrict__ counts,
    const int* __restrict__ csr, bf16* __restrict__ he) {
    int dst = blockIdx.x;
    int t = threadIdx.x;
    float dfv = toF(df[(size_t)dst * DIM + t]);
    int rs = rowst[dst], deg = counts[dst];
    float m = -1e30f, l = 0.f, acc = 0.f;
    for (int i = 0; i < deg; i++) {
        int src = csr[rs + i];
        float zv = toF(z[(size_t)src * DIM + t]);
        float p = zv * dfv;
#pragma unroll
        for (int off = 16; off > 0; off >>= 1) p += __shfl_xor(p, off, 32);
        float nm = fmaxf(m, p);
        float esc = __expf(m - nm);
        float pe = __expf(p - nm);
        l = l * esc + pe;
        acc = acc * esc + pe * zv;
        m = nm;
    }
    float hv = acc / l;
    hv = (hv > 0.f) ? hv : expm1f(hv);  // elu
    he[(size_t)dst * DIM + t] = fromF<bf16>(hv);
}

// ---- layernorm over 256, write bf16 ----
__global__ __launch_bounds__(256) void ln_k(const float* __restrict__ h1,
                                            const float* __restrict__ g,
                                            const float* __restrict__ b,
                                            bf16* __restrict__ xn) {
    int row = blockIdx.x, t = threadIdx.x;
    float x = h1[(size_t)row * DIM + t];
    float s1 = x, s2 = x * x;
#pragma unroll
    for (int off = 32; off > 0; off >>= 1) {
        s1 += __shfl_xor(s1, off, 64);
        s2 += __shfl_xor(s2, off, 64);
    }
    __shared__ float red[2][4];
    int w = t >> 6;
    if ((t & 63) == 0) {
        red[0][w] = s1;
        red[1][w] = s2;
    }
    __syncthreads();
    float t1 = red[0][0] + red[0][1] + red[0][2] + red[0][3];
    float t2 = red[1][0] + red[1][1] + red[1][2] + red[1][3];
    float mu = t1 * (1.f / DIM);
    float var = t2 * (1.f / DIM) - mu * mu;
    float v = (x - mu) * rsqrtf(var + 1e-6f) * g[t] + b[t];
    xn[(size_t)row * DIM + t] = fromF<bf16>(v);
}

extern "C" void kernel_launch(void* const* d_in, const int* in_sizes, int n_in,
                              void* d_out, int out_size, void* d_ws, size_t ws_size,
                              hipStream_t stream) {
    const float* s = (const float*)d_in[0];
    const float* e = (const float*)d_in[1];
    const float* dst_feat = (const float*)d_in[2];
    const float* fc_w = (const float*)d_in[3];
    const float* dstfeat_w = (const float*)d_in[4];
    const float* proj_w = (const float*)d_in[5];
    const float* proj_b = (const float*)d_in[6];
    const float* ln_g = (const float*)d_in[7];
    const float* ln_b = (const float*)d_in[8];
    const float* w1 = (const float*)d_in[9];
    const float* b1 = (const float*)d_in[10];
    const float* w2 = (const float*)d_in[11];
    const float* b2 = (const float*)d_in[12];
    const int* edge_src = (const int*)d_in[13];
    const int* edge_dst = (const int*)d_in[14];
    float* out = (float*)d_out;

    char* base = (char*)d_ws;
    size_t off = 0;
    auto alloc = [&](size_t bytes) -> char* {
        char* p = base + off;
        off = (off + bytes + 255) & ~(size_t)255;
        return p;
    };
    float* Wz = (float*)alloc((size_t)DIM * DIM * 4);
    float* Wd = (float*)alloc((size_t)FEAT_N * DIM * 4);
    int* counts = (int*)alloc((size_t)NS_N * 4);
    int* rowst = (int*)alloc((size_t)NS_N * 4);
    int* cursor = (int*)alloc((size_t)NS_N * 4);
    int* chunks = (int*)alloc(1024);
    int* csr = (int*)alloc((size_t)EDG_N * 4);
    bf16* zB = (bf16*)alloc((size_t)NE_N * DIM * 2);   // 51.2 MB
    bf16* dfB = (bf16*)alloc((size_t)NS_N * DIM * 2);  // 51.2 MB (contiguous with heB)
    bf16* heB = (bf16*)alloc((size_t)NS_N * DIM * 2);  // 51.2 MB
    float* h1F = (float*)alloc((size_t)NS_N * DIM * 4);
    bf16* xnB = zB;   // z dead after attn
    bf16* a1B = dfB;  // df+he dead after proj; 102.4 MB contiguous

    hipMemsetAsync(counts, 0, (size_t)NS_N * 4, stream);
    repack_w<<<(DIM * 256 + 255) / 256, 256, 0, stream>>>(fc_w, Wz, DIM);
    repack_w<<<(FEAT_N * 256 + 255) / 256, 256, 0, stream>>>(dstfeat_w, Wd, FEAT_N);
    count_edges<<<(EDG_N + 255) / 256, 256, 0, stream>>>(edge_dst, counts);
    int nchunk = (NS_N + 511) / 512;
    scan_block<<<nchunk, 512, 0, stream>>>(counts, rowst, chunks);
    scan_chunks<<<1, 256, 0, stream>>>(chunks, nchunk);
    add_offsets<<<(NS_N + 255) / 256, 256, 0, stream>>>(rowst, chunks, cursor);
    scatter_edges<<<(EDG_N + 255) / 256, 256, 0, stream>>>(edge_src, edge_dst, cursor, csr);

    dim3 blk(256);
    // z = e @ Wz  -> bf16
    gemm_k<float, bf16, false, false, false><<<dim3(DIM / 128, (NE_N + 127) / 128), blk, 0, stream>>>(
        e, nullptr, DIM, Wz, nullptr, nullptr, zB, NE_N, DIM, DIM);
    // df = dst_feat @ Wd -> bf16
    gemm_k<float, bf16, false, false, false><<<dim3(DIM / 128, (NS_N + 127) / 128), blk, 0, stream>>>(
        dst_feat, nullptr, FEAT_N, Wd, nullptr, nullptr, dfB, NS_N, DIM, FEAT_N);
    // fused segment-softmax attention + elu
    attn_k<<<NS_N, 256, 0, stream>>>(zB, dfB, rowst, counts, csr, heB);
    // h1 = [he | s] @ proj_w + proj_b  -> fp32
    gemm_k<bf16, float, true, false, false><<<dim3(DIM / 128, (NS_N + 127) / 128), blk, 0, stream>>>(
        heB, s, DIM, proj_w, proj_b, nullptr, h1F, NS_N, DIM, 2 * DIM);
    // xn = LN(h1) -> bf16
    ln_k<<<NS_N, 256, 0, stream>>>(h1F, ln_g, ln_b, xnB);
    // a1 = gelu(xn @ w1 + b1) -> bf16
    gemm_k<bf16, bf16, true, true, false><<<dim3(DFF_N / 128, (NS_N + 127) / 128), blk, 0, stream>>>(
        xnB, nullptr, DIM, w1, b1, nullptr, a1B, NS_N, DFF_N, DIM);
    // out = h1 + (a1 @ w2 + b2) -> fp32
    gemm_k<bf16, float, true, false, true><<<dim3(DIM / 128, (NS_N + 127) / 128), blk, 0, stream>>>(
        a1B, nullptr, DFF_N, w2, b2, h1F, out, NS_N, DIM, DFF_N);
}

// Round 2
// 1323.309 us; speedup vs baseline: 1.7788x; 1.7788x over previous
//
#include <hip/hip_runtime.h>
#include <hip/hip_bf16.h>
#include <stdint.h>

#define NS_N 100000
#define NE_N 100000
#define MP 100096      // rows padded to multiple of 128 for MFMA tiles
#define EDG_N 1600000
#define DIM 256
#define FEAT_N 64
#define DFF_N 512

using bf16 = __hip_bfloat16;
typedef __bf16 bf16x8 __attribute__((ext_vector_type(8)));
typedef float f32x4 __attribute__((ext_vector_type(4)));

__device__ __forceinline__ float toF(float x) { return x; }
__device__ __forceinline__ float toF(bf16 x) { return __bfloat162float(x); }

template <class T> __device__ __forceinline__ T fromF(float x);
template <> __device__ __forceinline__ float fromF<float>(float x) { return x; }
template <> __device__ __forceinline__ bf16 fromF<bf16>(float x) { return __float2bfloat16(x); }

// async global->LDS, 16B per lane; lds dest must be wave-uniform base (lane*16 implicit)
__device__ __forceinline__ void g2l16(const void* g, void* l) {
    __builtin_amdgcn_global_load_lds((const __attribute__((address_space(1))) unsigned int*)g,
                                     (__attribute__((address_space(3))) unsigned int*)l, 16, 0, 0);
}

// ---- fp32 -> bf16 convert (4-wide), dst row stride S ----
__global__ void cvt_f2b4(const float4* __restrict__ src, bf16* __restrict__ dst,
                         int M, int K4, int S) {
    int idx = blockIdx.x * 256 + threadIdx.x;
    if (idx >= M * K4) return;
    int r = idx / K4, c = (idx - r * K4) * 4;
    float4 v = src[idx];
    union { ushort4 u; bf16 h[4]; } p;
    p.h[0] = fromF<bf16>(v.x); p.h[1] = fromF<bf16>(v.y);
    p.h[2] = fromF<bf16>(v.z); p.h[3] = fromF<bf16>(v.w);
    *(ushort4*)&dst[(size_t)r * S + c] = p.u;
}

// ---- weight transpose fp32 [K][N] -> bf16 [N][K] ----
__global__ void tr_w(const float* __restrict__ src, bf16* __restrict__ dst, int K, int N) {
    int idx = blockIdx.x * 256 + threadIdx.x;
    if (idx >= K * N) return;
    int n = idx / K, k = idx - n * K;
    dst[idx] = fromF<bf16>(src[(size_t)k * N + n]);
}

// ---- per-head weight [8][K][32] -> bf16 [256][K] ----
__global__ void tr_headw(const float* __restrict__ src, bf16* __restrict__ dst, int K) {
    int idx = blockIdx.x * 256 + threadIdx.x;
    if (idx >= 256 * K) return;
    int n = idx / K, k = idx - n * K;
    dst[idx] = fromF<bf16>(src[((size_t)(n >> 5) * K + k) * 32 + (n & 31)]);
}

// ---- CSR build ----
__global__ void count_edges(const int* __restrict__ edst, int* __restrict__ counts) {
    int t = blockIdx.x * 256 + threadIdx.x;
    if (t < EDG_N) atomicAdd(&counts[edst[t]], 1);
}

__global__ void scan_block(const int* __restrict__ counts, int* __restrict__ partial,
                           int* __restrict__ chunk) {
    __shared__ int sh[512];
    int i = blockIdx.x * 512 + threadIdx.x;
    int v = (i < NS_N) ? counts[i] : 0;
    sh[threadIdx.x] = v;
    __syncthreads();
    for (int off = 1; off < 512; off <<= 1) {
        int x = (threadIdx.x >= off) ? sh[threadIdx.x - off] : 0;
        __syncthreads();
        sh[threadIdx.x] += x;
        __syncthreads();
    }
    if (i < NS_N) partial[i] = sh[threadIdx.x] - v;  // exclusive
    if (threadIdx.x == 511) chunk[blockIdx.x] = sh[511];
}

__global__ void scan_chunks(int* __restrict__ chunk, int nc) {
    __shared__ int sh[256];
    int t = threadIdx.x;
    int v = (t < nc) ? chunk[t] : 0;
    sh[t] = v;
    __syncthreads();
    for (int off = 1; off < 256; off <<= 1) {
        int x = (t >= off) ? sh[t - off] : 0;
        __syncthreads();
        sh[t] += x;
        __syncthreads();
    }
    if (t < nc) chunk[t] = sh[t] - v;  // exclusive
}

__global__ void add_offsets(int* __restrict__ rowst, const int* __restrict__ chunk,
                            int* __restrict__ cursor) {
    int i = blockIdx.x * 256 + threadIdx.x;
    if (i < NS_N) {
        int r = rowst[i] + chunk[i >> 9];
        rowst[i] = r;
        cursor[i] = r;
    }
}

__global__ void scatter_edges(const int* __restrict__ esrc, const int* __restrict__ edst,
                              int* __restrict__ cursor, int* __restrict__ csr) {
    int t = blockIdx.x * 256 + threadIdx.x;
    if (t < EDG_N) {
        int d = edst[t];
        int pos = atomicAdd(&cursor[d], 1);
        csr[pos] = esrc[t];
    }
}

// ---- MFMA GEMM: C[M,N] = epi(A[M,K] @ BT[N,K]^T + bias) (+ res) ----
// A padded to >= ceil(M/128)*128 rows. 128x128 tile, 4 waves, each wave 64x64
// as 4x4 grid of 16x16x32 bf16 MFMA tiles. global_load_lds width-16 staging.
template <class TC, bool BIAS, bool GELU, bool RES>
__global__ __launch_bounds__(256) void mfma_gemm(
    const bf16* __restrict__ A, const bf16* __restrict__ BT,
    const float* __restrict__ bias, const float* __restrict__ res,
    TC* __restrict__ C, int M, int N, int K) {
    __shared__ bf16 As[128 * 32];
    __shared__ bf16 Bs[128 * 32];
    const int tid = threadIdx.x;
    const int wave = tid >> 6, lane = tid & 63;
    const int m0 = blockIdx.y * 128, n0 = blockIdx.x * 128;
    const int wm = (wave >> 1) * 64, wn = (wave & 1) * 64;

    f32x4 acc[4][4];
    const f32x4 zero4 = {0.f, 0.f, 0.f, 0.f};
#pragma unroll
    for (int i = 0; i < 4; i++)
#pragma unroll
        for (int j = 0; j < 4; j++) acc[i][j] = zero4;

    // staging: chunk c (16 rows, 1KB) -> wave c%4 handles c and c+4.
    // lane l: row-in-chunk l>>2, col-chunk (l&3)*8 elems -> lds offset l*16B.
    const int sr = lane >> 2, sc = (lane & 3) * 8;
    const bf16* gA0 = A + (size_t)(m0 + wave * 16 + sr) * K + sc;
    const bf16* gA1 = A + (size_t)(m0 + 64 + wave * 16 + sr) * K + sc;
    const bf16* gB0 = BT + (size_t)(n0 + wave * 16 + sr) * K + sc;
    const bf16* gB1 = BT + (size_t)(n0 + 64 + wave * 16 + sr) * K + sc;
    bf16* lA0 = As + wave * 512;
    bf16* lA1 = As + (wave + 4) * 512;
    bf16* lB0 = Bs + wave * 512;
    bf16* lB1 = Bs + (wave + 4) * 512;

    const int fr = lane & 15, fq = (lane >> 4) * 8;

    for (int k0 = 0; k0 < K; k0 += 32) {
        __syncthreads();  // prior iter's ds_reads done before overwrite
        g2l16(gA0, lA0);
        g2l16(gA1, lA1);
        g2l16(gB0, lB0);
        g2l16(gB1, lB1);
        gA0 += 32; gA1 += 32; gB0 += 32; gB1 += 32;
        __syncthreads();  // staging complete (vmcnt drained by barrier)
        bf16x8 af[4], bfv[4];
#pragma unroll
        for (int mt = 0; mt < 4; mt++)
            af[mt] = *(const bf16x8*)&As[(wm + mt * 16 + fr) * 32 + fq];
#pragma unroll
        for (int nt = 0; nt < 4; nt++)
            bfv[nt] = *(const bf16x8*)&Bs[(wn + nt * 16 + fr) * 32 + fq];
#pragma unroll
        for (int mt = 0; mt < 4; mt++)
#pragma unroll
            for (int nt = 0; nt < 4; nt++)
                acc[mt][nt] = __builtin_amdgcn_mfma_f32_16x16x32_bf16(af[mt], bfv[nt], acc[mt][nt], 0, 0, 0);
    }

    // C/D layout: col = lane&15, row = (lane>>4)*4 + reg
    const int q4 = (lane >> 4) * 4;
#pragma unroll
    for (int nt = 0; nt < 4; nt++) {
        const int col = n0 + wn + nt * 16 + fr;
        const float bv = BIAS ? bias[col] : 0.f;
#pragma unroll
        for (int mt = 0; mt < 4; mt++) {
#pragma unroll
            for (int r = 0; r < 4; r++) {
                int row = m0 + wm + mt * 16 + q4 + r;
                if (row < M) {
                    float v = acc[mt][nt][r] + bv;
                    if (GELU) {
                        float x = v;
                        v = 0.5f * x * (1.f + tanhf(0.7978845608028654f * (x + 0.044715f * x * x * x)));
                    }
                    if (RES) v += res[(size_t)row * N + col];
                    C[(size_t)row * N + col] = fromF<TC>(v);
                }
            }
        }
    }
}

// ---- fused edge-softmax attention + elu, 2-edge batched online softmax ----
// one block per dst; thread t = channel; head = t>>5 (32-lane subgroup).
// writes into concat buffer (row stride 512, left half).
__global__ __launch_bounds__(256) void attn_k(
    const bf16* __restrict__ z, const bf16* __restrict__ df,
    const int* __restrict__ rowst, const int* __restrict__ counts,
    const int* __restrict__ csr, bf16* __restrict__ he) {
    int dst = blockIdx.x;
    int t = threadIdx.x;
    float dfv = toF(df[(size_t)dst * DIM + t]);
    int rs = rowst[dst], deg = counts[dst];
    float m = -1e30f, l = 0.f, acc = 0.f;
    int i = 0;
    for (; i + 2 <= deg; i += 2) {
        int s1 = csr[rs + i], s2 = csr[rs + i + 1];
        float z1 = toF(z[(size_t)s1 * DIM + t]);
        float z2 = toF(z[(size_t)s2 * DIM + t]);
        float p1 = z1 * dfv, p2 = z2 * dfv;
#pragma unroll
        for (int off = 16; off > 0; off >>= 1) {
            p1 += __shfl_xor(p1, off, 32);
            p2 += __shfl_xor(p2, off, 32);
        }
        float nm = fmaxf(m, fmaxf(p1, p2));
        float e0 = __expf(m - nm), e1 = __expf(p1 - nm), e2 = __expf(p2 - nm);
        l = l * e0 + e1 + e2;
        acc = acc * e0 + e1 * z1 + e2 * z2;
        m = nm;
    }
    if (i < deg) {
        int s1 = csr[rs + i];
        float z1 = toF(z[(size_t)s1 * DIM + t]);
        float p1 = z1 * dfv;
#pragma unroll
        for (int off = 16; off > 0; off >>= 1) p1 += __shfl_xor(p1, off, 32);
        float nm = fmaxf(m, p1);
        float e0 = __expf(m - nm), e1 = __expf(p1 - nm);
        l = l * e0 + e1;
        acc = acc * e0 + e1 * z1;
        m = nm;
    }
    float hv = acc / l;
    hv = (hv > 0.f) ? hv : expm1f(hv);  // elu
    he[(size_t)dst * 512 + t] = fromF<bf16>(hv);
}

// ---- layernorm over 256, write bf16 ----
__global__ __launch_bounds__(256) void ln_k(const float* __restrict__ h1,
                                            const float* __restrict__ g,
                                            const float* __restrict__ b,
                                            bf16* __restrict__ xn) {
    int row = blockIdx.x, t = threadIdx.x;
    float x = h1[(size_t)row * DIM + t];
    float s1 = x, s2 = x * x;
#pragma unroll
    for (int off = 32; off > 0; off >>= 1) {
        s1 += __shfl_xor(s1, off, 64);
        s2 += __shfl_xor(s2, off, 64);
    }
    __shared__ float red[2][4];
    int w = t >> 6;
    if ((t & 63) == 0) {
        red[0][w] = s1;
        red[1][w] = s2;
    }
    __syncthreads();
    float t1 = red[0][0] + red[0][1] + red[0][2] + red[0][3];
    float t2 = red[1][0] + red[1][1] + red[1][2] + red[1][3];
    float mu = t1 * (1.f / DIM);
    float var = t2 * (1.f / DIM) - mu * mu;
    float v = (x - mu) * rsqrtf(var + 1e-6f) * g[t] + b[t];
    xn[(size_t)row * DIM + t] = fromF<bf16>(v);
}

extern "C" void kernel_launch(void* const* d_in, const int* in_sizes, int n_in,
                              void* d_out, int out_size, void* d_ws, size_t ws_size,
                              hipStream_t stream) {
    const float* s = (const float*)d_in[0];
    const float* e = (const float*)d_in[1];
    const float* dst_feat = (const float*)d_in[2];
    const float* fc_w = (const float*)d_in[3];
    const float* dstfeat_w = (const float*)d_in[4];
    const float* proj_w = (const float*)d_in[5];
    const float* proj_b = (const float*)d_in[6];
    const float* ln_g = (const float*)d_in[7];
    const float* ln_b = (const float*)d_in[8];
    const float* w1 = (const float*)d_in[9];
    const float* b1 = (const float*)d_in[10];
    const float* w2 = (const float*)d_in[11];
    const float* b2 = (const float*)d_in[12];
    const int* edge_src = (const int*)d_in[13];
    const int* edge_dst = (const int*)d_in[14];
    float* out = (float*)d_out;

    char* base = (char*)d_ws;
    size_t off = 0;
    auto alloc = [&](size_t bytes) -> char* {
        char* p = base + off;
        off = (off + bytes + 255) & ~(size_t)255;
        return p;
    };
    // bf16 transposed weights [N][K]
    bf16* fcT = (bf16*)alloc((size_t)256 * 256 * 2);
    bf16* dfeatT = (bf16*)alloc((size_t)256 * 64 * 2);
    bf16* projT = (bf16*)alloc((size_t)256 * 512 * 2);
    bf16* w1T = (bf16*)alloc((size_t)512 * 256 * 2);
    bf16* w2T = (bf16*)alloc((size_t)256 * 512 * 2);
    int* counts = (int*)alloc((size_t)NS_N * 4);
    int* rowst = (int*)alloc((size_t)NS_N * 4);
    int* cursor = (int*)alloc((size_t)NS_N * 4);
    int* chunks = (int*)alloc(1024);
    int* csr = (int*)alloc((size_t)EDG_N * 4);
    bf16* eB = (bf16*)alloc((size_t)MP * DIM * 2);      // 51.2 MB; reused as xnB
    bf16* zB = (bf16*)alloc((size_t)MP * DIM * 2);      // 51.2 MB \ contiguous ->
    bf16* dfB = (bf16*)alloc((size_t)MP * DIM * 2);     // 51.2 MB / a1B (MP x 512)
    bf16* dfeatB = (bf16*)alloc((size_t)MP * FEAT_N * 2);
    bf16* catB = (bf16*)alloc((size_t)MP * 512 * 2);    // [he | s]
    float* h1F = (float*)alloc((size_t)MP * DIM * 4);
    bf16* xnB = eB;   // e dead after gemm1
    bf16* a1B = zB;   // z,df dead after attn; spans zB+dfB = MP*512 bf16

    hipMemsetAsync(counts, 0, (size_t)NS_N * 4, stream);
    // weight prep
    tr_headw<<<(256 * 256 + 255) / 256, 256, 0, stream>>>(fc_w, fcT, 256);
    tr_headw<<<(256 * 64 + 255) / 256, 256, 0, stream>>>(dstfeat_w, dfeatT, 64);
    tr_w<<<(512 * 256 + 255) / 256, 256, 0, stream>>>(proj_w, projT, 512, 256);
    tr_w<<<(256 * 512 + 255) / 256, 256, 0, stream>>>(w1, w1T, 256, 512);
    tr_w<<<(512 * 256 + 255) / 256, 256, 0, stream>>>(w2, w2T, 512, 256);
    // activation converts
    cvt_f2b4<<<(NE_N * 64 + 255) / 256, 256, 0, stream>>>((const float4*)e, eB, NE_N, 64, DIM);
    cvt_f2b4<<<(NS_N * 16 + 255) / 256, 256, 0, stream>>>((const float4*)dst_feat, dfeatB, NS_N, 16, FEAT_N);
    cvt_f2b4<<<(NS_N * 64 + 255) / 256, 256, 0, stream>>>((const float4*)s, catB + 256, NS_N, 64, 512);
    // CSR
    count_edges<<<(EDG_N + 255) / 256, 256, 0, stream>>>(edge_dst, counts);
    int nchunk = (NS_N + 511) / 512;
    scan_block<<<nchunk, 512, 0, stream>>>(counts, rowst, chunks);
    scan_chunks<<<1, 256, 0, stream>>>(chunks, nchunk);
    add_offsets<<<(NS_N + 255) / 256, 256, 0, stream>>>(rowst, chunks, cursor);
    scatter_edges<<<(EDG_N + 255) / 256, 256, 0, stream>>>(edge_src, edge_dst, cursor, csr);

    dim3 blk(256);
    const int gy = MP / 128;  // 782
    // z = e @ Wz -> bf16
    mfma_gemm<bf16, false, false, false><<<dim3(2, gy), blk, 0, stream>>>(
        eB, fcT, nullptr, nullptr, zB, NE_N, DIM, DIM);
    // df = dst_feat @ Wd -> bf16
    mfma_gemm<bf16, false, false, false><<<dim3(2, gy), blk, 0, stream>>>(
        dfeatB, dfeatT, nullptr, nullptr, dfB, NS_N, DIM, FEAT_N);
    // attention -> catB left half
    attn_k<<<NS_N, 256, 0, stream>>>(zB, dfB, rowst, counts, csr, catB);
    // h1 = cat(he,s) @ proj_w + proj_b -> fp32
    mfma_gemm<float, true, false, false><<<dim3(2, gy), blk, 0, stream>>>(
        catB, projT, proj_b, nullptr, h1F, NS_N, DIM, 2 * DIM);
    // xn = LN(h1) -> bf16
    ln_k<<<NS_N, 256, 0, stream>>>(h1F, ln_g, ln_b, xnB);
    // a1 = gelu(xn @ w1 + b1) -> bf16
    mfma_gemm<bf16, true, true, false><<<dim3(4, gy), blk, 0, stream>>>(
        xnB, w1T, b1, nullptr, a1B, NS_N, DFF_N, DIM);
    // out = h1 + (a1 @ w2 + b2) -> fp32
    mfma_gemm<float, true, false, true><<<dim3(2, gy), blk, 0, stream>>>(
        a1B, w2T, b2, h1F, out, NS_N, DIM, DFF_N);
}